// Round 3
// baseline (1126.499 us; speedup 1.0000x reference)
//
#include <hip/hip_runtime.h>

// FusedLoRAQKV on MI355X (gfx950).
// Y_p = X @ (W_p + 2 * B_p @ A_p)^T  for p in {Q,K,V}
//
// Pipeline:
//   1. cvt_x:    X fp32 -> bf16
//   2. merge_w3: W' = bf16(W + 2*B@A), all three projections in one launch
//   3. gemm8:    256x256 8-phase, BK=64, 8 waves, mfma_f32_32x32x16_bf16,
//                XOR-swizzled LDS (verified 0 bank conflicts), cross-phase
//                register read-ahead, counted vmcnt(4), setprio, XCD swizzle.

typedef unsigned short u16;
typedef __attribute__((ext_vector_type(4)))  float  f32x4;
typedef __attribute__((ext_vector_type(16))) float  f32x16;
typedef __attribute__((ext_vector_type(8)))  __bf16 bf16x8;
typedef __attribute__((ext_vector_type(8)))  short  s16x8;

#define MDIM 8192
#define NDIM 4096
#define KDIM 4096

__device__ __forceinline__ u16 f2bf(float f) {
    union { float f; unsigned int u; } v;
    v.f = f;
    unsigned int r = v.u + 0x7FFFu + ((v.u >> 16) & 1u);  // RNE
    return (u16)(r >> 16);
}

// ---------------- Kernel 1: X fp32 -> bf16 ----------------
__global__ void __launch_bounds__(256) cvt_x_kernel(const float* __restrict__ X,
                                                    u16* __restrict__ Xb, int nvec8) {
    int stride = gridDim.x * blockDim.x;
    for (int i = blockIdx.x * blockDim.x + threadIdx.x; i < nvec8; i += stride) {
        f32x4 x0 = ((const f32x4*)X)[2 * i];
        f32x4 x1 = ((const f32x4*)X)[2 * i + 1];
        s16x8 o;
        o[0] = (short)f2bf(x0[0]); o[1] = (short)f2bf(x0[1]);
        o[2] = (short)f2bf(x0[2]); o[3] = (short)f2bf(x0[3]);
        o[4] = (short)f2bf(x1[0]); o[5] = (short)f2bf(x1[1]);
        o[6] = (short)f2bf(x1[2]); o[7] = (short)f2bf(x1[3]);
        ((s16x8*)Xb)[i] = o;
    }
}

// ---------------- Kernel 2: W' = bf16(W + 2*B@A), z = projection ----------------
__global__ void __launch_bounds__(256) merge_w3_kernel(const float* __restrict__ QW,
                                                       const float* __restrict__ QA,
                                                       const float* __restrict__ QB,
                                                       const float* __restrict__ KW,
                                                       const float* __restrict__ KA,
                                                       const float* __restrict__ KB,
                                                       const float* __restrict__ VW,
                                                       const float* __restrict__ VA,
                                                       const float* __restrict__ VB,
                                                       u16* __restrict__ WbAll) {
    const int z = blockIdx.z;
    const float* W  = (z == 0) ? QW : (z == 1) ? KW : VW;
    const float* A  = (z == 0) ? QA : (z == 1) ? KA : VA;
    const float* Bm = (z == 0) ? QB : (z == 1) ? KB : VB;
    u16* Wb = WbAll + (size_t)z * NDIM * KDIM;

    __shared__ float As[16][64];
    const int t  = threadIdx.x;
    const int hb = blockIdx.x * 64;
    const int nb = blockIdx.y * 128;

    {   // stage A[16][hb:hb+64]
        int r = t >> 4, c = (t & 15) * 4;
        *(f32x4*)&As[r][c] = *(const f32x4*)&A[r * 4096 + hb + c];
    }
    __syncthreads();

    const int hl = (t & 7) * 8;
    const int n0 = nb + (t >> 3) * 4;

    float bv[4][16];
    float s[4][8];
#pragma unroll
    for (int i = 0; i < 4; i++) {
        const float* br = &Bm[(size_t)(n0 + i) * 16];
#pragma unroll
        for (int r = 0; r < 16; r++) bv[i][r] = 2.0f * br[r];
        f32x4 w0 = *(const f32x4*)&W[(size_t)(n0 + i) * 4096 + hb + hl];
        f32x4 w1 = *(const f32x4*)&W[(size_t)(n0 + i) * 4096 + hb + hl + 4];
        s[i][0] = w0[0]; s[i][1] = w0[1]; s[i][2] = w0[2]; s[i][3] = w0[3];
        s[i][4] = w1[0]; s[i][5] = w1[1]; s[i][6] = w1[2]; s[i][7] = w1[3];
    }
#pragma unroll
    for (int r = 0; r < 16; r++) {
        f32x4 a0 = *(const f32x4*)&As[r][hl];
        f32x4 a1 = *(const f32x4*)&As[r][hl + 4];
#pragma unroll
        for (int i = 0; i < 4; i++) {
            s[i][0] += bv[i][r] * a0[0]; s[i][1] += bv[i][r] * a0[1];
            s[i][2] += bv[i][r] * a0[2]; s[i][3] += bv[i][r] * a0[3];
            s[i][4] += bv[i][r] * a1[0]; s[i][5] += bv[i][r] * a1[1];
            s[i][6] += bv[i][r] * a1[2]; s[i][7] += bv[i][r] * a1[3];
        }
    }
#pragma unroll
    for (int i = 0; i < 4; i++) {
        s16x8 o;
#pragma unroll
        for (int j = 0; j < 8; j++) o[j] = (short)f2bf(s[i][j]);
        *(s16x8*)&Wb[(size_t)(n0 + i) * 4096 + hb + hl] = o;
    }
}

// ---------------- Kernel 3: 256x256 8-phase GEMM, 32x32x16 MFMA ----------------
// 8 waves (2M x 4N), per-wave 128x64 out: acc[4][2] f32x16.
// LDS 128 KiB: A[2][256][64] + B[2][256][64] bf16, XOR-swizzle chunk16B ^= row&7.
// Per K-tile (4 phases), quadrant q = (mi-pair, ni):
//   P1: rd b1       ; STG (t+1).Ah0 ; BAR ; MFMA aLo x b0 ; BAR
//   P2: rd aHi      ; STG (t+1).Ah1 ; BAR ; MFMA aLo x b1 ; BAR
//   P3:             ; STG (t+2).Bh0 ; BAR ; MFMA aHi x b0 ; BAR
//   P4: STG (t+2).Bh1 ; vmcnt(4) ; BAR ; rd-ahead aLo',b0' (next buf) ;
//                                        MFMA aHi x b1 ; BAR
// Cross-tile read-ahead sits behind the vmcnt-protected barrier (all waves'
// stages landed). Compiler inserts counted lgkmcnt before each MFMA use, so
// every quadrant waits on reads issued >= 1 phase earlier.

#define BM 256
#define BN 256
#define BK 64

#define BAR() __builtin_amdgcn_s_barrier()
#define WAIT_VM(n) asm volatile("s_waitcnt vmcnt(" #n ")" ::: "memory")
#define PRIO(p) __builtin_amdgcn_s_setprio(p)

__global__ void __launch_bounds__(512, 2) gemm8_kernel(const u16* __restrict__ Xb,
                                                       const u16* __restrict__ Wb,
                                                       float* __restrict__ out) {
    extern __shared__ char lds[];

    const int t    = threadIdx.x;
    const int lane = t & 63;
    const int w    = t >> 6;      // wave 0..7
    const int wr   = w >> 2;      // M wave 0..1
    const int wn   = w & 3;       // N wave 0..3
    const int l31  = lane & 31;
    const int hi   = lane >> 5;   // k-half
    const int swz  = l31 & 7;

    // XCD-bijective remap: 1536 blocks = 8 XCDs x 192
    int wg = blockIdx.x;
    wg = (wg & 7) * 192 + (wg >> 3);
    const int z  = wg >> 9;
    const int r_ = wg & 511;
    const int nT = r_ & 15;
    const int mT = r_ >> 4;
    const int mBase = mT * BM;
    const int nBase = nT * BN;

    const u16* Wp = Wb + (size_t)z * NDIM * KDIM;
    const char* gA = (const char*)Xb + (size_t)mBase * (KDIM * 2);
    const char* gB = (const char*)Wp + (size_t)nBase * (KDIM * 2);

    char* ldsA0 = lds;
    char* ldsA1 = lds + 32768;
    char* ldsB0 = lds + 65536;
    char* ldsB1 = lds + 98304;

    // staging: 2 x global_load_lds(16B) per wave per half-tile, linear LDS dst,
    // source col pre-swizzled (inverse of read swizzle; involution)
    const int blkrow = lane >> 3;
    const int colswz = ((lane & 7) ^ blkrow) << 4;
    const size_t stg0 = (size_t)(((w << 1) | 0) * 8 + blkrow) * (KDIM * 2) + colswz;
    const size_t stg1 = (size_t)(((w << 1) | 1) * 8 + blkrow) * (KDIM * 2) + colswz;
    const int ldsStg0 = (((w << 1) | 0) << 10) + lane * 16;
    const int ldsStg1 = (((w << 1) | 1) << 10) + lane * 16;

#define STAGE(ldsTile, gtile, h, kt)                                              \
  { __builtin_amdgcn_global_load_lds(                                             \
        (const __attribute__((address_space(1))) void*)((gtile) + stg0 +          \
            (size_t)(h) * (128 * KDIM * 2) + (size_t)(kt) * 128),                 \
        (__attribute__((address_space(3))) void*)((ldsTile) + (h) * 16384 + ldsStg0), \
        16, 0, 0);                                                                \
    __builtin_amdgcn_global_load_lds(                                             \
        (const __attribute__((address_space(1))) void*)((gtile) + stg1 +          \
            (size_t)(h) * (128 * KDIM * 2) + (size_t)(kt) * 128),                 \
        (__attribute__((address_space(3))) void*)((ldsTile) + (h) * 16384 + ldsStg1), \
        16, 0, 0); }

    // ds_read: row = (panel + sub*32 + l31), byte = row*128 + ((ks*2+hi)^(l31&7))*16
    const int rA0 = (wr * 128 + l31) * 128;
    const int rB0 = (wn * 64 + l31) * 128;
#define RD_A(tile, mi, ks) (*(const bf16x8*)((tile) + rA0 + (mi) * 4096 + (((((ks) << 1) | hi) ^ swz) << 4)))
#define RD_B(tile, ni, ks) (*(const bf16x8*)((tile) + rB0 + (ni) * 4096 + (((((ks) << 1) | hi) ^ swz) << 4)))

    f32x16 acc[4][2] = {};
    bf16x8 aLo[2][4], aHi[2][4], bb[2][4];

#define MFMA_Q(AF, mbase, nidx)                                                    \
    PRIO(1);                                                                       \
    _Pragma("unroll") for (int ks = 0; ks < 4; ++ks)                               \
    _Pragma("unroll") for (int mi = 0; mi < 2; ++mi)                               \
      acc[(mbase) + mi][nidx] = __builtin_amdgcn_mfma_f32_32x32x16_bf16(           \
          AF[mi][ks], bb[nidx][ks], acc[(mbase) + mi][nidx], 0, 0, 0);             \
    PRIO(0);

#define PH1(pB, STG)                                                               \
  { _Pragma("unroll") for (int ks = 0; ks < 4; ++ks) bb[1][ks] = RD_B(pB, 1, ks);  \
    STG; BAR(); MFMA_Q(aLo, 0, 0) BAR(); }

#define PH2(pA, STG)                                                               \
  { _Pragma("unroll") for (int mi = 0; mi < 2; ++mi)                               \
    _Pragma("unroll") for (int ks = 0; ks < 4; ++ks)                               \
      aHi[mi][ks] = RD_A(pA, 2 + mi, ks);                                          \
    STG; BAR(); MFMA_Q(aLo, 0, 1) BAR(); }

#define PH3(STG)                                                                   \
  { STG; BAR(); MFMA_Q(aHi, 2, 0) BAR(); }

#define PH4(pAn, pBn, STG, VMW)                                                    \
  { STG; VMW; BAR();                                                               \
    _Pragma("unroll") for (int mi = 0; mi < 2; ++mi)                               \
    _Pragma("unroll") for (int ks = 0; ks < 4; ++ks)                               \
      aLo[mi][ks] = RD_A(pAn, mi, ks);                                             \
    _Pragma("unroll") for (int ks = 0; ks < 4; ++ks) bb[0][ks] = RD_B(pBn, 0, ks); \
    MFMA_Q(aHi, 2, 1) BAR(); }

#define PH4F()                                                                     \
  { BAR(); MFMA_Q(aHi, 2, 1) }

    // ---- prologue: t0 {Ah0,Ah1,Bh0,Bh1}; t1 {Bh0,Bh1} ----
    STAGE(ldsA0, gA, 0, 0); STAGE(ldsA0, gA, 1, 0);
    STAGE(ldsB0, gB, 0, 0); STAGE(ldsB0, gB, 1, 0);
    STAGE(ldsB1, gB, 0, 1); STAGE(ldsB1, gB, 1, 1);
    WAIT_VM(4);   // oldest 8 (= all of t0) landed
    BAR();
    // initial read: tile0 Q1 operands (aLo, b0)
#pragma unroll
    for (int mi = 0; mi < 2; ++mi)
#pragma unroll
        for (int ks = 0; ks < 4; ++ks) aLo[mi][ks] = RD_A(ldsA0, mi, ks);
#pragma unroll
    for (int ks = 0; ks < 4; ++ks) bb[0][ks] = RD_B(ldsB0, 0, ks);

    // ---- main loop: 31 iterations over tile pairs (t = 2i, 2i+1) ----
    for (int i = 0; i < 31; ++i) {
        const int tt = 2 * i;
        PH1(ldsB0,        STAGE(ldsA1, gA, 0, tt + 1));                 // (t+1).Ah0
        PH2(ldsA0,        STAGE(ldsA1, gA, 1, tt + 1));                 // (t+1).Ah1
        PH3(              STAGE(ldsB0, gB, 0, tt + 2));                 // (t+2).Bh0
        PH4(ldsA1, ldsB1, STAGE(ldsB0, gB, 1, tt + 2), WAIT_VM(4));     // (t+2).Bh1
        PH1(ldsB1,        STAGE(ldsA0, gA, 0, tt + 2));                 // (t+2).Ah0
        PH2(ldsA1,        STAGE(ldsA0, gA, 1, tt + 2));                 // (t+2).Ah1
        PH3(              STAGE(ldsB1, gB, 0, tt + 3));                 // (t+3).Bh0
        PH4(ldsA0, ldsB0, STAGE(ldsB1, gB, 1, tt + 3), WAIT_VM(4));     // (t+3).Bh1
    }

    // ---- peeled last pair (t = 62, 63) ----
    PH1(ldsB0,        STAGE(ldsA1, gA, 0, 63));
    PH2(ldsA0,        STAGE(ldsA1, gA, 1, 63));
    PH3( );
    PH4(ldsA1, ldsB1, , WAIT_VM(0));
    PH1(ldsB1, );
    PH2(ldsA1, );
    PH3( );
    PH4F();

    // ---- epilogue: 32x32 C/D layout: col = lane&31, row = (reg&3)+8*(reg>>2)+4*hi ----
    float* C = out + (size_t)z * MDIM * NDIM;
#pragma unroll
    for (int mi = 0; mi < 4; ++mi) {
#pragma unroll
        for (int ni = 0; ni < 2; ++ni) {
            const int col  = nBase + wn * 64 + ni * 32 + l31;
            const int rowb = mBase + wr * 128 + mi * 32 + 4 * hi;
            f32x16 v = acc[mi][ni];
#pragma unroll
            for (int reg = 0; reg < 16; ++reg) {
                const int row = rowb + (reg & 3) + 8 * (reg >> 2);
                C[(size_t)row * NDIM + col] = v[reg];
            }
        }
    }
}

// ---------------- host launch ----------------
extern "C" void kernel_launch(void* const* d_in, const int* in_sizes, int n_in,
                              void* d_out, int out_size, void* d_ws, size_t ws_size,
                              hipStream_t stream) {
    const float* X  = (const float*)d_in[0];
    const float* QW = (const float*)d_in[1];
    const float* QA = (const float*)d_in[2];
    const float* QB = (const float*)d_in[3];
    const float* KW = (const float*)d_in[4];
    const float* KA = (const float*)d_in[5];
    const float* KB = (const float*)d_in[6];
    const float* VW = (const float*)d_in[7];
    const float* VA = (const float*)d_in[8];
    const float* VB = (const float*)d_in[9];
    float* out = (float*)d_out;

    u16* Xb = (u16*)d_ws;                                        // 64 MiB
    u16* Wb = (u16*)((char*)d_ws + (size_t)MDIM * KDIM * 2);     // 3 x 32 MiB

    (void)hipFuncSetAttribute((const void*)gemm8_kernel,
                              hipFuncAttributeMaxDynamicSharedMemorySize, 131072);

    cvt_x_kernel<<<2048, 256, 0, stream>>>(X, Xb, (MDIM * KDIM) / 8);

    dim3 wgrid(4096 / 64, 4096 / 128, 3);
    merge_w3_kernel<<<wgrid, 256, 0, stream>>>(QW, QA, QB, KW, KA, KB, VW, VA, VB, Wb);

    gemm8_kernel<<<dim3(16 * 32 * 3), dim3(512), 131072, stream>>>(Xb, Wb, out);
}

// Round 4
// 853.973 us; speedup vs baseline: 1.3191x; 1.3191x over previous
//
#include <hip/hip_runtime.h>

// FusedLoRAQKV on MI355X (gfx950).
// Y_p = X @ (W_p + 2 * B_p @ A_p)^T  for p in {Q,K,V}
//
// Pipeline:
//   1. cvt_x:    X fp32 -> bf16
//   2. merge_w3: W' = bf16(W + 2*B@A), all three projections, one launch
//   3. gemm8:    256x256 8-phase, BK=64, 8 waves, mfma_f32_16x16x32_bf16
//                (f32x4 accs -- 32x32/f32x16 spilled, R3 post-mortem),
//                XOR-swizzled LDS (0 conflicts, R2-verified), CROSS-PHASE
//                READ-AHEAD (all ds_reads >=1 phase before consuming MFMA,
//                compiler-counted lgkmcnt), vmcnt(4) at P4/P8, setprio,
//                bijective XCD swizzle.

typedef unsigned short u16;
typedef __attribute__((ext_vector_type(4))) float  f32x4;
typedef __attribute__((ext_vector_type(8))) __bf16 bf16x8;
typedef __attribute__((ext_vector_type(8))) short  s16x8;

#define MDIM 8192
#define NDIM 4096
#define KDIM 4096

__device__ __forceinline__ u16 f2bf(float f) {
    union { float f; unsigned int u; } v;
    v.f = f;
    unsigned int r = v.u + 0x7FFFu + ((v.u >> 16) & 1u);  // RNE
    return (u16)(r >> 16);
}

// ---------------- Kernel 1: X fp32 -> bf16 ----------------
__global__ void __launch_bounds__(256) cvt_x_kernel(const float* __restrict__ X,
                                                    u16* __restrict__ Xb, int nvec8) {
    int stride = gridDim.x * blockDim.x;
    for (int i = blockIdx.x * blockDim.x + threadIdx.x; i < nvec8; i += stride) {
        f32x4 x0 = ((const f32x4*)X)[2 * i];
        f32x4 x1 = ((const f32x4*)X)[2 * i + 1];
        s16x8 o;
        o[0] = (short)f2bf(x0[0]); o[1] = (short)f2bf(x0[1]);
        o[2] = (short)f2bf(x0[2]); o[3] = (short)f2bf(x0[3]);
        o[4] = (short)f2bf(x1[0]); o[5] = (short)f2bf(x1[1]);
        o[6] = (short)f2bf(x1[2]); o[7] = (short)f2bf(x1[3]);
        ((s16x8*)Xb)[i] = o;
    }
}

// ---------------- Kernel 2: W' = bf16(W + 2*B@A), z = projection ----------------
__global__ void __launch_bounds__(256) merge_w3_kernel(const float* __restrict__ QW,
                                                       const float* __restrict__ QA,
                                                       const float* __restrict__ QB,
                                                       const float* __restrict__ KW,
                                                       const float* __restrict__ KA,
                                                       const float* __restrict__ KB,
                                                       const float* __restrict__ VW,
                                                       const float* __restrict__ VA,
                                                       const float* __restrict__ VB,
                                                       u16* __restrict__ WbAll) {
    const int z = blockIdx.z;
    const float* W  = (z == 0) ? QW : (z == 1) ? KW : VW;
    const float* A  = (z == 0) ? QA : (z == 1) ? KA : VA;
    const float* Bm = (z == 0) ? QB : (z == 1) ? KB : VB;
    u16* Wb = WbAll + (size_t)z * NDIM * KDIM;

    __shared__ float As[16][64];
    const int t  = threadIdx.x;
    const int hb = blockIdx.x * 64;
    const int nb = blockIdx.y * 128;

    {   // stage A[16][hb:hb+64]
        int r = t >> 4, c = (t & 15) * 4;
        *(f32x4*)&As[r][c] = *(const f32x4*)&A[r * 4096 + hb + c];
    }
    __syncthreads();

    const int hl = (t & 7) * 8;
    const int n0 = nb + (t >> 3) * 4;

    float bv[4][16];
    float s[4][8];
#pragma unroll
    for (int i = 0; i < 4; i++) {
        const float* br = &Bm[(size_t)(n0 + i) * 16];
#pragma unroll
        for (int r = 0; r < 16; r++) bv[i][r] = 2.0f * br[r];
        f32x4 w0 = *(const f32x4*)&W[(size_t)(n0 + i) * 4096 + hb + hl];
        f32x4 w1 = *(const f32x4*)&W[(size_t)(n0 + i) * 4096 + hb + hl + 4];
        s[i][0] = w0[0]; s[i][1] = w0[1]; s[i][2] = w0[2]; s[i][3] = w0[3];
        s[i][4] = w1[0]; s[i][5] = w1[1]; s[i][6] = w1[2]; s[i][7] = w1[3];
    }
#pragma unroll
    for (int r = 0; r < 16; r++) {
        f32x4 a0 = *(const f32x4*)&As[r][hl];
        f32x4 a1 = *(const f32x4*)&As[r][hl + 4];
#pragma unroll
        for (int i = 0; i < 4; i++) {
            s[i][0] += bv[i][r] * a0[0]; s[i][1] += bv[i][r] * a0[1];
            s[i][2] += bv[i][r] * a0[2]; s[i][3] += bv[i][r] * a0[3];
            s[i][4] += bv[i][r] * a1[0]; s[i][5] += bv[i][r] * a1[1];
            s[i][6] += bv[i][r] * a1[2]; s[i][7] += bv[i][r] * a1[3];
        }
    }
#pragma unroll
    for (int i = 0; i < 4; i++) {
        s16x8 o;
#pragma unroll
        for (int j = 0; j < 8; j++) o[j] = (short)f2bf(s[i][j]);
        *(s16x8*)&Wb[(size_t)(n0 + i) * 4096 + hb + hl] = o;
    }
}

// ---------------- Kernel 3: 256x256 8-phase GEMM, read-ahead ----------------
// 8 waves (2M x 4N), per-wave 128x64 out, acc[8][4] f32x4 (16x16x32 MFMA).
// LDS 128 KiB: A[2][256][64] + B[2][256][64] bf16, 16B-chunk XOR swizzle
// (chunk ^= row&7), staged via linear-dst global_load_lds + pre-swizzled
// global source (involution, rule 21).
//
// Per tile t (4 phases), quadrants Q1=m0-3 x n0-1, Q2=m0-3 x n2-3,
// Q3=m4-7 x n0-1, Q4=m4-7 x n2-3. All operand reads >=1 phase ahead:
//   P1: rd aR2[0,1](t); STG; BAR; Q1; BAR
//   P2: rd aR2[2,3](t); STG; BAR; Q2; BAR
//   P3:                 STG; BAR; Q3; BAR
//   P4: STG; vmcnt(4); BAR; rd aR1(t+1)+bR[0,1](t+1); Q4; rd bR[2,3](t+1); BAR
// Stage slots (iteration = tiles T,T+1): P1/P2: (T+1).Ah0/Ah1; P3/P4:
// (T+2).Bh0/Bh1; P5/P6: (T+2).Ah0/Ah1; P7/P8: (T+3).Bh0/Bh1.
// vmcnt(4) at P4 drains P1/P2 (A(T+1)) and everything older; at P8 drains
// P5/P6 (A(T+2)) + P3/P4 (B(T+2)). Write-after-read verified per slot under
// read-ahead drain semantics (each buffer re-staged >=1 phase after the
// MFMA that drains its last reads + an intervening barrier).

#define BM 256
#define BN 256
#define BK 64

#define BAR() __builtin_amdgcn_s_barrier()
#define WAIT_VM(n) asm volatile("s_waitcnt vmcnt(" #n ")" ::: "memory")
#define PRIO(p) __builtin_amdgcn_s_setprio(p)

__global__ void __launch_bounds__(512, 2) gemm8_kernel(const u16* __restrict__ Xb,
                                                       const u16* __restrict__ Wb,
                                                       float* __restrict__ out) {
    extern __shared__ char lds[];

    const int t    = threadIdx.x;
    const int lane = t & 63;
    const int w    = t >> 6;      // wave 0..7
    const int wr   = w >> 2;      // M wave 0..1
    const int wn   = w & 3;       // N wave 0..3
    const int lr   = lane & 15;
    const int lkq  = lane >> 4;
    const int lr7  = lr & 7;

    // XCD-bijective remap: 1536 blocks = 8 XCDs x 192
    int wg = blockIdx.x;
    wg = (wg & 7) * 192 + (wg >> 3);
    const int z  = wg >> 9;
    const int r_ = wg & 511;
    const int nT = r_ & 15;
    const int mT = r_ >> 4;
    const int mBase = mT * BM;
    const int nBase = nT * BN;

    const u16* Wp = Wb + (size_t)z * NDIM * KDIM;
    const char* gA = (const char*)Xb + (size_t)mBase * (KDIM * 2);
    const char* gB = (const char*)Wp + (size_t)nBase * (KDIM * 2);

    char* ldsA0 = lds;
    char* ldsA1 = lds + 32768;
    char* ldsB0 = lds + 65536;
    char* ldsB1 = lds + 98304;

    // staging: 2 x global_load_lds(16B)/wave/half-tile, linear LDS dst,
    // pre-swizzled global source column
    const int blkrow = lane >> 3;
    const int colswz = ((lane & 7) ^ blkrow) << 4;
    const size_t stg0 = (size_t)(((w << 1) | 0) * 8 + blkrow) * (KDIM * 2) + colswz;
    const size_t stg1 = (size_t)(((w << 1) | 1) * 8 + blkrow) * (KDIM * 2) + colswz;
    const int ldsStg0 = (((w << 1) | 0) << 10) + lane * 16;
    const int ldsStg1 = (((w << 1) | 1) << 10) + lane * 16;

#define STAGE(ldsTile, gtile, h, kt)                                              \
  { __builtin_amdgcn_global_load_lds(                                             \
        (const __attribute__((address_space(1))) void*)((gtile) + stg0 +          \
            (size_t)(h) * (128 * KDIM * 2) + (size_t)(kt) * 128),                 \
        (__attribute__((address_space(3))) void*)((ldsTile) + (h) * 16384 + ldsStg0), \
        16, 0, 0);                                                                \
    __builtin_amdgcn_global_load_lds(                                             \
        (const __attribute__((address_space(1))) void*)((gtile) + stg1 +          \
            (size_t)(h) * (128 * KDIM * 2) + (size_t)(kt) * 128),                 \
        (__attribute__((address_space(3))) void*)((ldsTile) + (h) * 16384 + ldsStg1), \
        16, 0, 0); }

    // ds_read: row*128 + (((kk<<2)|lkq) ^ (row&7))*16 ; row&7 == lr7
    const int csA = (lkq << 4) ^ (lr7 << 4);
    const int rA0 = (wr * 128 + lr) * 128;
    const int rB0 = (wn * 64 + lr) * 128;
#define RD_A(tile, mi, kk) (*(const bf16x8*)((tile) + rA0 + (mi) * 2048 + (((kk) << 6) ^ csA)))
#define RD_B(tile, ni, kk) (*(const bf16x8*)((tile) + rB0 + (ni) * 2048 + (((kk) << 6) ^ csA)))

    f32x4 acc[8][4] = {};
    bf16x8 aR1[4][2], aR2[4][2], bR[4][2];

#define MFMA_Q(AF, mbase, nbase)                                                   \
    PRIO(1);                                                                       \
    _Pragma("unroll") for (int mi = 0; mi < 4; ++mi)                               \
    _Pragma("unroll") for (int ni = 0; ni < 2; ++ni)                               \
    _Pragma("unroll") for (int kk = 0; kk < 2; ++kk)                               \
      acc[(mbase) + mi][(nbase) + ni] = __builtin_amdgcn_mfma_f32_16x16x32_bf16(   \
          AF[mi][kk], bR[(nbase) + ni][kk], acc[(mbase) + mi][(nbase) + ni], 0, 0, 0); \
    PRIO(0);

// P1: read aR2[0,1](t) = A rows mi 4,5; MFMA Q1 (aR1 x bR[0,1])
#define PH1(pA, STG)                                                               \
  { aR2[0][0] = RD_A(pA, 4, 0); aR2[0][1] = RD_A(pA, 4, 1);                        \
    aR2[1][0] = RD_A(pA, 5, 0); aR2[1][1] = RD_A(pA, 5, 1);                        \
    STG; BAR(); MFMA_Q(aR1, 0, 0) BAR(); }

// P2: read aR2[2,3](t); MFMA Q2 (aR1 x bR[2,3])
#define PH2(pA, STG)                                                               \
  { aR2[2][0] = RD_A(pA, 6, 0); aR2[2][1] = RD_A(pA, 6, 1);                        \
    aR2[3][0] = RD_A(pA, 7, 0); aR2[3][1] = RD_A(pA, 7, 1);                        \
    STG; BAR(); MFMA_Q(aR2, 4, 0) BAR(); }

// NOTE: PH2 must issue Q2 = (aR1, bR[2,3]); PH3 issues Q3 = (aR2, bR[0,1]).
// (macros below keep the quadrant order straight)
#undef PH2
#define PH2(pA, STG)                                                               \
  { aR2[2][0] = RD_A(pA, 6, 0); aR2[2][1] = RD_A(pA, 6, 1);                        \
    aR2[3][0] = RD_A(pA, 7, 0); aR2[3][1] = RD_A(pA, 7, 1);                        \
    STG; BAR(); MFMA_Q(aR1, 0, 2) BAR(); }

// P3: MFMA Q3 (aR2 x bR[0,1])
#define PH3(STG)                                                                   \
  { STG; BAR(); MFMA_Q(aR2, 4, 0) BAR(); }

// P4: vmcnt; BAR; read-ahead aR1(t+1) + bR[0,1](t+1); MFMA Q4 (aR2 x bR[2,3]);
//     read-ahead bR[2,3](t+1) (after Q4 -- WAR)
#define PH4(pAn, pBn, STG, VMW)                                                    \
  { STG; VMW; BAR();                                                               \
    _Pragma("unroll") for (int mi = 0; mi < 4; ++mi) {                             \
      aR1[mi][0] = RD_A(pAn, mi, 0); aR1[mi][1] = RD_A(pAn, mi, 1); }              \
    bR[0][0] = RD_B(pBn, 0, 0); bR[0][1] = RD_B(pBn, 0, 1);                        \
    bR[1][0] = RD_B(pBn, 1, 0); bR[1][1] = RD_B(pBn, 1, 1);                        \
    MFMA_Q(aR2, 4, 2)                                                              \
    bR[2][0] = RD_B(pBn, 2, 0); bR[2][1] = RD_B(pBn, 2, 1);                        \
    bR[3][0] = RD_B(pBn, 3, 0); bR[3][1] = RD_B(pBn, 3, 1);                        \
    BAR(); }

#define PH4F()                                                                     \
  { BAR(); MFMA_Q(aR2, 4, 2) }

    // ---- prologue: stage A(0), B(0), B(1); pre-read tile0 aR1 + bR ----
    STAGE(ldsA0, gA, 0, 0); STAGE(ldsA0, gA, 1, 0);
    STAGE(ldsB0, gB, 0, 0); STAGE(ldsB0, gB, 1, 0);
    STAGE(ldsB1, gB, 0, 1); STAGE(ldsB1, gB, 1, 1);
    WAIT_VM(4);   // A(0), B(0) landed (B(1)'s 4 loads may remain)
    BAR();
#pragma unroll
    for (int mi = 0; mi < 4; ++mi) {
        aR1[mi][0] = RD_A(ldsA0, mi, 0); aR1[mi][1] = RD_A(ldsA0, mi, 1);
    }
#pragma unroll
    for (int ni = 0; ni < 4; ++ni) {
        bR[ni][0] = RD_B(ldsB0, ni, 0); bR[ni][1] = RD_B(ldsB0, ni, 1);
    }

    // ---- main loop: 31 iterations (tiles T=2i, T+1), T = 0..60 ----
    for (int i = 0; i < 31; ++i) {
        const int T = 2 * i;
        PH1(ldsA0,        STAGE(ldsA1, gA, 0, T + 1));                 // (T+1).Ah0
        PH2(ldsA0,        STAGE(ldsA1, gA, 1, T + 1));                 // (T+1).Ah1
        PH3(              STAGE(ldsB0, gB, 0, T + 2));                 // (T+2).Bh0
        PH4(ldsA1, ldsB1, STAGE(ldsB0, gB, 1, T + 2), WAIT_VM(4));     // (T+2).Bh1
        PH1(ldsA1,        STAGE(ldsA0, gA, 0, T + 2));                 // (T+2).Ah0
        PH2(ldsA1,        STAGE(ldsA0, gA, 1, T + 2));                 // (T+2).Ah1
        PH3(              STAGE(ldsB1, gB, 0, T + 3));                 // (T+3).Bh0
        PH4(ldsA0, ldsB0, STAGE(ldsB1, gB, 1, T + 3), WAIT_VM(4));     // (T+3).Bh1
    }

    // ---- peeled last pair (tiles 62, 63) ----
    PH1(ldsA0,        STAGE(ldsA1, gA, 0, 63));                        // 63.Ah0
    PH2(ldsA0,        STAGE(ldsA1, gA, 1, 63));                        // 63.Ah1
    PH3( );
    PH4(ldsA1, ldsB1, , WAIT_VM(0));                                   // RA(63)
    PH1(ldsA1, );
    PH2(ldsA1, );
    PH3( );
    PH4F();

    // ---- epilogue: C/D layout col = lane&15, row = (lane>>4)*4 + reg ----
    float* C = out + (size_t)z * MDIM * NDIM;
#pragma unroll
    for (int mi = 0; mi < 8; ++mi) {
#pragma unroll
        for (int ni = 0; ni < 4; ++ni) {
            const int col  = nBase + wn * 64 + ni * 16 + lr;
            const int row0 = mBase + wr * 128 + mi * 16 + lkq * 4;
            f32x4 v = acc[mi][ni];
#pragma unroll
            for (int j = 0; j < 4; ++j)
                C[(size_t)(row0 + j) * NDIM + col] = v[j];
        }
    }
}

// ---------------- host launch ----------------
extern "C" void kernel_launch(void* const* d_in, const int* in_sizes, int n_in,
                              void* d_out, int out_size, void* d_ws, size_t ws_size,
                              hipStream_t stream) {
    const float* X  = (const float*)d_in[0];
    const float* QW = (const float*)d_in[1];
    const float* QA = (const float*)d_in[2];
    const float* QB = (const float*)d_in[3];
    const float* KW = (const float*)d_in[4];
    const float* KA = (const float*)d_in[5];
    const float* KB = (const float*)d_in[6];
    const float* VW = (const float*)d_in[7];
    const float* VA = (const float*)d_in[8];
    const float* VB = (const float*)d_in[9];
    float* out = (float*)d_out;

    u16* Xb = (u16*)d_ws;                                        // 64 MiB
    u16* Wb = (u16*)((char*)d_ws + (size_t)MDIM * KDIM * 2);     // 3 x 32 MiB

    (void)hipFuncSetAttribute((const void*)gemm8_kernel,
                              hipFuncAttributeMaxDynamicSharedMemorySize, 131072);

    cvt_x_kernel<<<2048, 256, 0, stream>>>(X, Xb, (MDIM * KDIM) / 8);

    dim3 wgrid(4096 / 64, 4096 / 128, 3);
    merge_w3_kernel<<<wgrid, 256, 0, stream>>>(QW, QA, QB, KW, KA, KB, VW, VA, VB, Wb);

    gemm8_kernel<<<dim3(16 * 32 * 3), dim3(512), 131072, stream>>>(Xb, Wb, out);
}

// Round 5
// 807.031 us; speedup vs baseline: 1.3959x; 1.0582x over previous
//
#include <hip/hip_runtime.h>

// FusedLoRAQKV on MI355X (gfx950).
// Y_p = X @ (W_p + 2 * B_p @ A_p)^T  for p in {Q,K,V}
//
// Pipeline:
//   1. cvt_x:    X fp32 -> bf16
//   2. merge_w3: W' = bf16(W + 2*B@A), all three projections, one launch
//   3. gemm8:    256x256 8-phase, BK=64, 8 waves, mfma_f32_16x16x32_bf16,
//                XOR-swizzled LDS (0 conflicts, R2-verified), SAME-PHASE reads
//                (R4 read-ahead spilled: +25MB scratch writes), balanced
//                12/8/4/0 read distribution, lgkmcnt(8) hint on 12-read phase,
//                vmcnt(4)@P4 / vmcnt(6)@P8, setprio, bijective XCD swizzle,
//                NON-TEMPORAL C stores (keep A/B panels resident in L3).

typedef unsigned short u16;
typedef __attribute__((ext_vector_type(4))) float  f32x4;
typedef __attribute__((ext_vector_type(8))) __bf16 bf16x8;
typedef __attribute__((ext_vector_type(8))) short  s16x8;

#define MDIM 8192
#define NDIM 4096
#define KDIM 4096

__device__ __forceinline__ u16 f2bf(float f) {
    union { float f; unsigned int u; } v;
    v.f = f;
    unsigned int r = v.u + 0x7FFFu + ((v.u >> 16) & 1u);  // RNE
    return (u16)(r >> 16);
}

// ---------------- Kernel 1: X fp32 -> bf16 ----------------
__global__ void __launch_bounds__(256) cvt_x_kernel(const float* __restrict__ X,
                                                    u16* __restrict__ Xb, int nvec8) {
    int stride = gridDim.x * blockDim.x;
    for (int i = blockIdx.x * blockDim.x + threadIdx.x; i < nvec8; i += stride) {
        f32x4 x0 = ((const f32x4*)X)[2 * i];
        f32x4 x1 = ((const f32x4*)X)[2 * i + 1];
        s16x8 o;
        o[0] = (short)f2bf(x0[0]); o[1] = (short)f2bf(x0[1]);
        o[2] = (short)f2bf(x0[2]); o[3] = (short)f2bf(x0[3]);
        o[4] = (short)f2bf(x1[0]); o[5] = (short)f2bf(x1[1]);
        o[6] = (short)f2bf(x1[2]); o[7] = (short)f2bf(x1[3]);
        ((s16x8*)Xb)[i] = o;
    }
}

// ---------------- Kernel 2: W' = bf16(W + 2*B@A), z = projection ----------------
__global__ void __launch_bounds__(256) merge_w3_kernel(const float* __restrict__ QW,
                                                       const float* __restrict__ QA,
                                                       const float* __restrict__ QB,
                                                       const float* __restrict__ KW,
                                                       const float* __restrict__ KA,
                                                       const float* __restrict__ KB,
                                                       const float* __restrict__ VW,
                                                       const float* __restrict__ VA,
                                                       const float* __restrict__ VB,
                                                       u16* __restrict__ WbAll) {
    const int z = blockIdx.z;
    const float* W  = (z == 0) ? QW : (z == 1) ? KW : VW;
    const float* A  = (z == 0) ? QA : (z == 1) ? KA : VA;
    const float* Bm = (z == 0) ? QB : (z == 1) ? KB : VB;
    u16* Wb = WbAll + (size_t)z * NDIM * KDIM;

    __shared__ float As[16][64];
    const int t  = threadIdx.x;
    const int hb = blockIdx.x * 64;
    const int nb = blockIdx.y * 128;

    {   // stage A[16][hb:hb+64]
        int r = t >> 4, c = (t & 15) * 4;
        *(f32x4*)&As[r][c] = *(const f32x4*)&A[r * 4096 + hb + c];
    }
    __syncthreads();

    const int hl = (t & 7) * 8;
    const int n0 = nb + (t >> 3) * 4;

    float bv[4][16];
    float s[4][8];
#pragma unroll
    for (int i = 0; i < 4; i++) {
        const float* br = &Bm[(size_t)(n0 + i) * 16];
#pragma unroll
        for (int r = 0; r < 16; r++) bv[i][r] = 2.0f * br[r];
        f32x4 w0 = *(const f32x4*)&W[(size_t)(n0 + i) * 4096 + hb + hl];
        f32x4 w1 = *(const f32x4*)&W[(size_t)(n0 + i) * 4096 + hb + hl + 4];
        s[i][0] = w0[0]; s[i][1] = w0[1]; s[i][2] = w0[2]; s[i][3] = w0[3];
        s[i][4] = w1[0]; s[i][5] = w1[1]; s[i][6] = w1[2]; s[i][7] = w1[3];
    }
#pragma unroll
    for (int r = 0; r < 16; r++) {
        f32x4 a0 = *(const f32x4*)&As[r][hl];
        f32x4 a1 = *(const f32x4*)&As[r][hl + 4];
#pragma unroll
        for (int i = 0; i < 4; i++) {
            s[i][0] += bv[i][r] * a0[0]; s[i][1] += bv[i][r] * a0[1];
            s[i][2] += bv[i][r] * a0[2]; s[i][3] += bv[i][r] * a0[3];
            s[i][4] += bv[i][r] * a1[0]; s[i][5] += bv[i][r] * a1[1];
            s[i][6] += bv[i][r] * a1[2]; s[i][7] += bv[i][r] * a1[3];
        }
    }
#pragma unroll
    for (int i = 0; i < 4; i++) {
        s16x8 o;
#pragma unroll
        for (int j = 0; j < 8; j++) o[j] = (short)f2bf(s[i][j]);
        *(s16x8*)&Wb[(size_t)(n0 + i) * 4096 + hb + hl] = o;
    }
}

// ---------------- Kernel 3: 256x256 8-phase GEMM ----------------
// 8 waves (2M x 4N), per-wave 128x64 out, acc[8][4] f32x4 (16x16x32 MFMA).
// LDS 128 KiB: A[2][256][64] + B[2][256][64] bf16, 16B-chunk XOR swizzle
// (chunk ^= row&7), linear-dst global_load_lds + pre-swizzled source.
//
// Per tile (4 phases), SAME-PHASE reads, balanced 12/8/4/0:
//   P1: rd aR1(8) + bR01(4); STG; lgkm(8); BAR; lgkm0; Q1=aR1 x bR01; BAR
//   P2: rd bR23(4) + aR2a(4); STG; BAR; lgkm0; Q2=aR1 x bR23; BAR
//   P3: rd aR2b(4);           STG; BAR; lgkm0; Q3=aR2 x bR01; BAR
//   P4: STG; vmcnt; BAR; Q4=aR2 x bR23; BAR
//
// Buffer read windows: A-buf read P1,P2,P3 (pre-bar) -> writable from P4;
// B-buf read P1,P2 -> writable from P3. Stage slots (iter = tiles T,T+1):
//   P1: A(T+1).Ah1   [ldsA1: last read prev-P7 -> OK]
//   P3: B(T+2).Bh0   [ldsB0 writable from P3]
//   P4: B(T+2).Bh1
//   P5: A(T+2).Ah0   [ldsA0 writable from P4; P5 OK]
//   P6: A(T+2).Ah1
//   P7: B(T+3).Bh0   [ldsB1: last read P6 -> OK]
//   P8: B(T+3).Bh1 + A(T+3).Ah0  [ldsA1: last read P7 -> OK]
// vmcnt audit (steady state, 2 loads/STAGE):
//   entering P1: 6 in flight (B(T+1) 4 + A(T+1).Ah0 2)
//   P4 wait: 6 + P1,P3,P4 = 12 -> vmcnt(4) drains 8 = B(T+1)+A(T+1) full
//            (needed at P5/P6 reads); leftover 4 = B(T+2)
//   P8 wait: 4 + P5,P6,P7,P8(4) = 14 -> vmcnt(6) drains 8 = B(T+2)+A(T+2)
//            (needed at next P1/P2); leftover 6 = B(T+3)+A(T+3).Ah0  [OK]

#define BM 256
#define BN 256
#define BK 64

#define BAR() __builtin_amdgcn_s_barrier()
#define WAIT_LGKM0() asm volatile("s_waitcnt lgkmcnt(0)" ::: "memory")
#define LGKM_HINT8() asm volatile("s_waitcnt lgkmcnt(8)" ::: "memory")
#define WAIT_VM(n) asm volatile("s_waitcnt vmcnt(" #n ")" ::: "memory")
#define PRIO(p) __builtin_amdgcn_s_setprio(p)

__global__ void __launch_bounds__(512, 2) gemm8_kernel(const u16* __restrict__ Xb,
                                                       const u16* __restrict__ Wb,
                                                       float* __restrict__ out) {
    extern __shared__ char lds[];

    const int t    = threadIdx.x;
    const int lane = t & 63;
    const int w    = t >> 6;      // wave 0..7
    const int wr   = w >> 2;      // M wave 0..1
    const int wn   = w & 3;       // N wave 0..3
    const int lr   = lane & 15;
    const int lkq  = lane >> 4;
    const int lr7  = lr & 7;

    // XCD-bijective remap: 1536 blocks = 8 XCDs x 192
    int wg = blockIdx.x;
    wg = (wg & 7) * 192 + (wg >> 3);
    const int z  = wg >> 9;
    const int r_ = wg & 511;
    const int nT = r_ & 15;
    const int mT = r_ >> 4;
    const int mBase = mT * BM;
    const int nBase = nT * BN;

    const u16* Wp = Wb + (size_t)z * NDIM * KDIM;
    const char* gA = (const char*)Xb + (size_t)mBase * (KDIM * 2);
    const char* gB = (const char*)Wp + (size_t)nBase * (KDIM * 2);

    char* ldsA0 = lds;
    char* ldsA1 = lds + 32768;
    char* ldsB0 = lds + 65536;
    char* ldsB1 = lds + 98304;

    // staging: 2 x global_load_lds(16B)/wave/half-tile, linear LDS dst,
    // pre-swizzled global source column (involution, rule 21)
    const int blkrow = lane >> 3;
    const int colswz = ((lane & 7) ^ blkrow) << 4;
    const size_t stg0 = (size_t)(((w << 1) | 0) * 8 + blkrow) * (KDIM * 2) + colswz;
    const size_t stg1 = (size_t)(((w << 1) | 1) * 8 + blkrow) * (KDIM * 2) + colswz;
    const int ldsStg0 = (((w << 1) | 0) << 10) + lane * 16;
    const int ldsStg1 = (((w << 1) | 1) << 10) + lane * 16;

#define STAGE(ldsTile, gtile, h, kt)                                              \
  { __builtin_amdgcn_global_load_lds(                                             \
        (const __attribute__((address_space(1))) void*)((gtile) + stg0 +          \
            (size_t)(h) * (128 * KDIM * 2) + (size_t)(kt) * 128),                 \
        (__attribute__((address_space(3))) void*)((ldsTile) + (h) * 16384 + ldsStg0), \
        16, 0, 0);                                                                \
    __builtin_amdgcn_global_load_lds(                                             \
        (const __attribute__((address_space(1))) void*)((gtile) + stg1 +          \
            (size_t)(h) * (128 * KDIM * 2) + (size_t)(kt) * 128),                 \
        (__attribute__((address_space(3))) void*)((ldsTile) + (h) * 16384 + ldsStg1), \
        16, 0, 0); }

    // ds_read: row*128 + (((kk<<2)|lkq) ^ (row&7))*16 ; row&7 == lr7
    const int csA = (lkq << 4) ^ (lr7 << 4);
    const int rA0 = (wr * 128 + lr) * 128;
    const int rB0 = (wn * 64 + lr) * 128;
#define RD_A(tile, mi, kk) (*(const bf16x8*)((tile) + rA0 + (mi) * 2048 + (((kk) << 6) ^ csA)))
#define RD_B(tile, ni, kk) (*(const bf16x8*)((tile) + rB0 + (ni) * 2048 + (((kk) << 6) ^ csA)))

    f32x4 acc[8][4] = {};
    bf16x8 aR1[4][2], aR2[4][2], bR[4][2];

#define MFMA_Q(AF, mbase, nbase)                                                   \
    PRIO(1);                                                                       \
    _Pragma("unroll") for (int mi = 0; mi < 4; ++mi)                               \
    _Pragma("unroll") for (int ni = 0; ni < 2; ++ni)                               \
    _Pragma("unroll") for (int kk = 0; kk < 2; ++kk)                               \
      acc[(mbase) + mi][(nbase) + ni] = __builtin_amdgcn_mfma_f32_16x16x32_bf16(   \
          AF[mi][kk], bR[(nbase) + ni][kk], acc[(mbase) + mi][(nbase) + ni], 0, 0, 0); \
    PRIO(0);

// P1: rd aR1 (A mi0-3, 8) + bR01 (4) = 12 reads; Q1 = aR1 x bR[0,1]
#define PH1(pA, pB, STG)                                                           \
  { _Pragma("unroll") for (int mi = 0; mi < 4; ++mi) {                             \
      aR1[mi][0] = RD_A(pA, mi, 0); aR1[mi][1] = RD_A(pA, mi, 1); }                \
    bR[0][0] = RD_B(pB, 0, 0); bR[0][1] = RD_B(pB, 0, 1);                          \
    bR[1][0] = RD_B(pB, 1, 0); bR[1][1] = RD_B(pB, 1, 1);                          \
    STG; LGKM_HINT8(); BAR(); WAIT_LGKM0(); MFMA_Q(aR1, 0, 0) BAR(); }

// P2: rd bR23 (4) + aR2a (A mi4,5, 4) = 8 reads; Q2 = aR1 x bR[2,3]
#define PH2(pA, pB, STG)                                                           \
  { bR[2][0] = RD_B(pB, 2, 0); bR[2][1] = RD_B(pB, 2, 1);                          \
    bR[3][0] = RD_B(pB, 3, 0); bR[3][1] = RD_B(pB, 3, 1);                          \
    aR2[0][0] = RD_A(pA, 4, 0); aR2[0][1] = RD_A(pA, 4, 1);                        \
    aR2[1][0] = RD_A(pA, 5, 0); aR2[1][1] = RD_A(pA, 5, 1);                        \
    STG; BAR(); WAIT_LGKM0(); MFMA_Q(aR1, 0, 2) BAR(); }

// P3: rd aR2b (A mi6,7, 4); Q3 = aR2 x bR[0,1]
#define PH3(pA, STG)                                                               \
  { aR2[2][0] = RD_A(pA, 6, 0); aR2[2][1] = RD_A(pA, 6, 1);                        \
    aR2[3][0] = RD_A(pA, 7, 0); aR2[3][1] = RD_A(pA, 7, 1);                        \
    STG; BAR(); WAIT_LGKM0(); MFMA_Q(aR2, 4, 0) BAR(); }

// P4: no reads; Q4 = aR2 x bR[2,3]; vmcnt before barrier
#define PH4(STG, VMW)                                                              \
  { STG; VMW; BAR(); MFMA_Q(aR2, 4, 2) BAR(); }

#define PH4F()                                                                     \
  { BAR(); MFMA_Q(aR2, 4, 2) }

    // ---- prologue: A(0) full, B(0) full, B(1) full, A(1).Ah0 = 14 loads ----
    STAGE(ldsA0, gA, 0, 0); STAGE(ldsA0, gA, 1, 0);
    STAGE(ldsB0, gB, 0, 0); STAGE(ldsB0, gB, 1, 0);
    STAGE(ldsB1, gB, 0, 1); STAGE(ldsB1, gB, 1, 1);
    STAGE(ldsA1, gA, 0, 1);
    WAIT_VM(6);   // drain A(0)+B(0); leftover 6 = B(1)+A(1).Ah0
    BAR();

    // ---- main loop: 31 iterations (tiles T=2i, T+1), T = 0..60 ----
    for (int i = 0; i < 31; ++i) {
        const int T = 2 * i;
        PH1(ldsA0, ldsB0, STAGE(ldsA1, gA, 1, T + 1));                   // A(T+1).Ah1
        PH2(ldsA0, ldsB0, );                                             // no stage
        PH3(ldsA0,        STAGE(ldsB0, gB, 0, T + 2));                   // B(T+2).Bh0
        PH4(              STAGE(ldsB0, gB, 1, T + 2), WAIT_VM(4));       // B(T+2).Bh1
        PH1(ldsA1, ldsB1, STAGE(ldsA0, gA, 0, T + 2));                   // A(T+2).Ah0
        PH2(ldsA1, ldsB1, STAGE(ldsA0, gA, 1, T + 2));                   // A(T+2).Ah1
        PH3(ldsA1,        STAGE(ldsB1, gB, 0, T + 3));                   // B(T+3).Bh0
        PH4(              { STAGE(ldsB1, gB, 1, T + 3)                   // B(T+3).Bh1
                            STAGE(ldsA1, gA, 0, T + 3) }, WAIT_VM(6));   // A(T+3).Ah0
    }

    // ---- peeled last pair (tiles 62, 63) ----
    PH1(ldsA0, ldsB0, STAGE(ldsA1, gA, 1, 63));                          // A(63).Ah1
    PH2(ldsA0, ldsB0, );
    PH3(ldsA0, );
    PH4(, WAIT_VM(0));                                                   // all landed
    PH1(ldsA1, ldsB1, );
    PH2(ldsA1, ldsB1, );
    PH3(ldsA1, );
    PH4F();

    // ---- epilogue: C/D layout col = lane&15, row = (lane>>4)*4 + reg ----
    // Non-temporal stores: C is write-once; keep A/B panels resident in L3.
    float* C = out + (size_t)z * MDIM * NDIM;
#pragma unroll
    for (int mi = 0; mi < 8; ++mi) {
#pragma unroll
        for (int ni = 0; ni < 4; ++ni) {
            const int col  = nBase + wn * 64 + ni * 16 + lr;
            const int row0 = mBase + wr * 128 + mi * 16 + lkq * 4;
            f32x4 v = acc[mi][ni];
#pragma unroll
            for (int j = 0; j < 4; ++j)
                __builtin_nontemporal_store(v[j], &C[(size_t)(row0 + j) * NDIM + col]);
        }
    }
}

// ---------------- host launch ----------------
extern "C" void kernel_launch(void* const* d_in, const int* in_sizes, int n_in,
                              void* d_out, int out_size, void* d_ws, size_t ws_size,
                              hipStream_t stream) {
    const float* X  = (const float*)d_in[0];
    const float* QW = (const float*)d_in[1];
    const float* QA = (const float*)d_in[2];
    const float* QB = (const float*)d_in[3];
    const float* KW = (const float*)d_in[4];
    const float* KA = (const float*)d_in[5];
    const float* KB = (const float*)d_in[6];
    const float* VW = (const float*)d_in[7];
    const float* VA = (const float*)d_in[8];
    const float* VB = (const float*)d_in[9];
    float* out = (float*)d_out;

    u16* Xb = (u16*)d_ws;                                        // 64 MiB
    u16* Wb = (u16*)((char*)d_ws + (size_t)MDIM * KDIM * 2);     // 3 x 32 MiB

    (void)hipFuncSetAttribute((const void*)gemm8_kernel,
                              hipFuncAttributeMaxDynamicSharedMemorySize, 131072);

    cvt_x_kernel<<<2048, 256, 0, stream>>>(X, Xb, (MDIM * KDIM) / 8);

    dim3 wgrid(4096 / 64, 4096 / 128, 3);
    merge_w3_kernel<<<wgrid, 256, 0, stream>>>(QW, QA, QB, KW, KA, KB, VW, VA, VB, Wb);

    gemm8_kernel<<<dim3(16 * 32 * 3), dim3(512), 131072, stream>>>(Xb, Wb, out);
}

// Round 6
// 806.862 us; speedup vs baseline: 1.3961x; 1.0002x over previous
//
#include <hip/hip_runtime.h>

// FusedLoRAQKV on MI355X (gfx950).
// Y_p = X @ (W_p + 2 * B_p @ A_p)^T  for p in {Q,K,V}
//
// Pipeline:
//   1. cvt_x:    X fp32 -> bf16
//   2. merge_w3: W' = bf16(W + 2*B@A), all three projections, one launch
//   3. gemm8:    256x256 8-phase, BK=64, 8 waves, mfma_f32_16x16x32_bf16,
//                XOR-swizzled LDS (0 conflicts), 12/8/4/0 reads ordered by
//                consumption, NO explicit lgkm waits (plain-load ds_reads ->
//                compiler emits fine-grained counted lgkmcnt per consuming
//                MFMA; explicit drain-0 was costing ~190cyc/phase), counted
//                vmcnt(4)@P4 / vmcnt(6)@P8, setprio, bijective XCD swizzle,
//                normal C stores (nt stores caused +40% partial-line writes).

typedef unsigned short u16;
typedef __attribute__((ext_vector_type(4))) float  f32x4;
typedef __attribute__((ext_vector_type(8))) __bf16 bf16x8;
typedef __attribute__((ext_vector_type(8))) short  s16x8;

#define MDIM 8192
#define NDIM 4096
#define KDIM 4096

__device__ __forceinline__ u16 f2bf(float f) {
    union { float f; unsigned int u; } v;
    v.f = f;
    unsigned int r = v.u + 0x7FFFu + ((v.u >> 16) & 1u);  // RNE
    return (u16)(r >> 16);
}

// ---------------- Kernel 1: X fp32 -> bf16 ----------------
__global__ void __launch_bounds__(256) cvt_x_kernel(const float* __restrict__ X,
                                                    u16* __restrict__ Xb, int nvec8) {
    int stride = gridDim.x * blockDim.x;
    for (int i = blockIdx.x * blockDim.x + threadIdx.x; i < nvec8; i += stride) {
        f32x4 x0 = ((const f32x4*)X)[2 * i];
        f32x4 x1 = ((const f32x4*)X)[2 * i + 1];
        s16x8 o;
        o[0] = (short)f2bf(x0[0]); o[1] = (short)f2bf(x0[1]);
        o[2] = (short)f2bf(x0[2]); o[3] = (short)f2bf(x0[3]);
        o[4] = (short)f2bf(x1[0]); o[5] = (short)f2bf(x1[1]);
        o[6] = (short)f2bf(x1[2]); o[7] = (short)f2bf(x1[3]);
        ((s16x8*)Xb)[i] = o;
    }
}

// ---------------- Kernel 2: W' = bf16(W + 2*B@A), z = projection ----------------
__global__ void __launch_bounds__(256) merge_w3_kernel(const float* __restrict__ QW,
                                                       const float* __restrict__ QA,
                                                       const float* __restrict__ QB,
                                                       const float* __restrict__ KW,
                                                       const float* __restrict__ KA,
                                                       const float* __restrict__ KB,
                                                       const float* __restrict__ VW,
                                                       const float* __restrict__ VA,
                                                       const float* __restrict__ VB,
                                                       u16* __restrict__ WbAll) {
    const int z = blockIdx.z;
    const float* W  = (z == 0) ? QW : (z == 1) ? KW : VW;
    const float* A  = (z == 0) ? QA : (z == 1) ? KA : VA;
    const float* Bm = (z == 0) ? QB : (z == 1) ? KB : VB;
    u16* Wb = WbAll + (size_t)z * NDIM * KDIM;

    __shared__ float As[16][64];
    const int t  = threadIdx.x;
    const int hb = blockIdx.x * 64;
    const int nb = blockIdx.y * 128;

    {   // stage A[16][hb:hb+64]
        int r = t >> 4, c = (t & 15) * 4;
        *(f32x4*)&As[r][c] = *(const f32x4*)&A[r * 4096 + hb + c];
    }
    __syncthreads();

    const int hl = (t & 7) * 8;
    const int n0 = nb + (t >> 3) * 4;

    float bv[4][16];
    float s[4][8];
#pragma unroll
    for (int i = 0; i < 4; i++) {
        const float* br = &Bm[(size_t)(n0 + i) * 16];
#pragma unroll
        for (int r = 0; r < 16; r++) bv[i][r] = 2.0f * br[r];
        f32x4 w0 = *(const f32x4*)&W[(size_t)(n0 + i) * 4096 + hb + hl];
        f32x4 w1 = *(const f32x4*)&W[(size_t)(n0 + i) * 4096 + hb + hl + 4];
        s[i][0] = w0[0]; s[i][1] = w0[1]; s[i][2] = w0[2]; s[i][3] = w0[3];
        s[i][4] = w1[0]; s[i][5] = w1[1]; s[i][6] = w1[2]; s[i][7] = w1[3];
    }
#pragma unroll
    for (int r = 0; r < 16; r++) {
        f32x4 a0 = *(const f32x4*)&As[r][hl];
        f32x4 a1 = *(const f32x4*)&As[r][hl + 4];
#pragma unroll
        for (int i = 0; i < 4; i++) {
            s[i][0] += bv[i][r] * a0[0]; s[i][1] += bv[i][r] * a0[1];
            s[i][2] += bv[i][r] * a0[2]; s[i][3] += bv[i][r] * a0[3];
            s[i][4] += bv[i][r] * a1[0]; s[i][5] += bv[i][r] * a1[1];
            s[i][6] += bv[i][r] * a1[2]; s[i][7] += bv[i][r] * a1[3];
        }
    }
#pragma unroll
    for (int i = 0; i < 4; i++) {
        s16x8 o;
#pragma unroll
        for (int j = 0; j < 8; j++) o[j] = (short)f2bf(s[i][j]);
        *(s16x8*)&Wb[(size_t)(n0 + i) * 4096 + hb + hl] = o;
    }
}

// ---------------- Kernel 3: 256x256 8-phase GEMM ----------------
// 8 waves (2M x 4N), per-wave 128x64 out, acc[8][4] f32x4 (16x16x32 MFMA).
// LDS 128 KiB: A[2][256][64] + B[2][256][64] bf16, 16B-chunk XOR swizzle
// (chunk ^= row&7), linear-dst global_load_lds + pre-swizzled source.
//
// Per tile (4 phases). NO explicit lgkm waits: plain-load ds_reads let the
// compiler emit counted lgkmcnt per consuming MFMA. Reads ordered by
// consumption; cross-phase reads (P2's aR2a) never stall their own phase.
//   P1: rd a0,b0,a1,b1,a2,a3 (12); STG; BAR; Q1 = aR1 x bR01; BAR
//   P2: rd b2,b3,aR2a (8);        STG; BAR; Q2 = aR1 x bR23; BAR
//   P3: rd aR2b (4);              STG; BAR; Q3 = aR2 x bR01; BAR
//   P4: STG; vmcnt; BAR;               Q4 = aR2 x bR23; BAR
//
// WAR audit (no explicit lgkm): each buffer's last ds_read is consumed by an
// MFMA in the same phase (compiler wait => drained before that phase's end
// barrier); re-staging happens >= 1 barrier later:
//   B-buf: last read P2 (b23), consumed Q2 (P2) -> staged P3/P4.  OK
//   A-buf: last read P3 (aR2b), consumed Q3 (P3) -> staged P5/P6. OK
// Stage slots (iter = tiles T,T+1):
//   P1: A(T+1).Ah1 | P3: B(T+2).Bh0 | P4: B(T+2).Bh1 | P5: A(T+2).Ah0
//   P6: A(T+2).Ah1 | P7: B(T+3).Bh0 | P8: B(T+3).Bh1 + A(T+3).Ah0
// vmcnt audit (2 loads/STAGE): entering P1: 6 in flight (B(T+1) + A(T+1).Ah0).
//   P4: 6+3 staged = 12 -> vmcnt(4) drains B(T+1)+A(T+1) (read P5-P7);
//   P8: 4+5 staged = 14 -> vmcnt(6) drains B(T+2)+A(T+2) (read next P1-P3).

#define BM 256
#define BN 256
#define BK 64

#define BAR() __builtin_amdgcn_s_barrier()
#define WAIT_VM(n) asm volatile("s_waitcnt vmcnt(" #n ")" ::: "memory")
#define PRIO(p) __builtin_amdgcn_s_setprio(p)

__global__ void __launch_bounds__(512, 2) gemm8_kernel(const u16* __restrict__ Xb,
                                                       const u16* __restrict__ Wb,
                                                       float* __restrict__ out) {
    extern __shared__ char lds[];

    const int t    = threadIdx.x;
    const int lane = t & 63;
    const int w    = t >> 6;      // wave 0..7
    const int wr   = w >> 2;      // M wave 0..1
    const int wn   = w & 3;       // N wave 0..3
    const int lr   = lane & 15;
    const int lkq  = lane >> 4;
    const int lr7  = lr & 7;

    // XCD-bijective remap: 1536 blocks = 8 XCDs x 192
    int wg = blockIdx.x;
    wg = (wg & 7) * 192 + (wg >> 3);
    const int z  = wg >> 9;
    const int r_ = wg & 511;
    const int nT = r_ & 15;
    const int mT = r_ >> 4;
    const int mBase = mT * BM;
    const int nBase = nT * BN;

    const u16* Wp = Wb + (size_t)z * NDIM * KDIM;
    const char* gA = (const char*)Xb + (size_t)mBase * (KDIM * 2);
    const char* gB = (const char*)Wp + (size_t)nBase * (KDIM * 2);

    char* ldsA0 = lds;
    char* ldsA1 = lds + 32768;
    char* ldsB0 = lds + 65536;
    char* ldsB1 = lds + 98304;

    // staging: 2 x global_load_lds(16B)/wave/half-tile, linear LDS dst,
    // pre-swizzled global source column (involution, rule 21)
    const int blkrow = lane >> 3;
    const int colswz = ((lane & 7) ^ blkrow) << 4;
    const size_t stg0 = (size_t)(((w << 1) | 0) * 8 + blkrow) * (KDIM * 2) + colswz;
    const size_t stg1 = (size_t)(((w << 1) | 1) * 8 + blkrow) * (KDIM * 2) + colswz;
    const int ldsStg0 = (((w << 1) | 0) << 10) + lane * 16;
    const int ldsStg1 = (((w << 1) | 1) << 10) + lane * 16;

#define STAGE(ldsTile, gtile, h, kt)                                              \
  { __builtin_amdgcn_global_load_lds(                                             \
        (const __attribute__((address_space(1))) void*)((gtile) + stg0 +          \
            (size_t)(h) * (128 * KDIM * 2) + (size_t)(kt) * 128),                 \
        (__attribute__((address_space(3))) void*)((ldsTile) + (h) * 16384 + ldsStg0), \
        16, 0, 0);                                                                \
    __builtin_amdgcn_global_load_lds(                                             \
        (const __attribute__((address_space(1))) void*)((gtile) + stg1 +          \
            (size_t)(h) * (128 * KDIM * 2) + (size_t)(kt) * 128),                 \
        (__attribute__((address_space(3))) void*)((ldsTile) + (h) * 16384 + ldsStg1), \
        16, 0, 0); }

    // ds_read: row*128 + (((kk<<2)|lkq) ^ (row&7))*16 ; row&7 == lr7
    const int csA = (lkq << 4) ^ (lr7 << 4);
    const int rA0 = (wr * 128 + lr) * 128;
    const int rB0 = (wn * 64 + lr) * 128;
#define RD_A(tile, mi, kk) (*(const bf16x8*)((tile) + rA0 + (mi) * 2048 + (((kk) << 6) ^ csA)))
#define RD_B(tile, ni, kk) (*(const bf16x8*)((tile) + rB0 + (ni) * 2048 + (((kk) << 6) ^ csA)))

    f32x4 acc[8][4] = {};
    bf16x8 aR1[4][2], aR2[4][2], bR[4][2];

#define MFMA_Q(AF, mbase, nbase)                                                   \
    PRIO(1);                                                                       \
    _Pragma("unroll") for (int mi = 0; mi < 4; ++mi)                               \
    _Pragma("unroll") for (int ni = 0; ni < 2; ++ni)                               \
    _Pragma("unroll") for (int kk = 0; kk < 2; ++kk)                               \
      acc[(mbase) + mi][(nbase) + ni] = __builtin_amdgcn_mfma_f32_16x16x32_bf16(   \
          AF[mi][kk], bR[(nbase) + ni][kk], acc[(mbase) + mi][(nbase) + ni], 0, 0, 0); \
    PRIO(0);

// P1: 12 reads in consumption order (a0,b0,a1,b1,a2,a3); Q1 = aR1 x bR[0,1]
#define PH1(pA, pB, STG)                                                           \
  { aR1[0][0] = RD_A(pA, 0, 0); aR1[0][1] = RD_A(pA, 0, 1);                        \
    bR[0][0]  = RD_B(pB, 0, 0); bR[0][1]  = RD_B(pB, 0, 1);                        \
    aR1[1][0] = RD_A(pA, 1, 0); aR1[1][1] = RD_A(pA, 1, 1);                        \
    bR[1][0]  = RD_B(pB, 1, 0); bR[1][1]  = RD_B(pB, 1, 1);                        \
    aR1[2][0] = RD_A(pA, 2, 0); aR1[2][1] = RD_A(pA, 2, 1);                        \
    aR1[3][0] = RD_A(pA, 3, 0); aR1[3][1] = RD_A(pA, 3, 1);                        \
    STG; BAR(); MFMA_Q(aR1, 0, 0) BAR(); }

// P2: b23 first (consumed by Q2), then aR2a (consumed in P3 -- no stall here)
#define PH2(pA, pB, STG)                                                           \
  { bR[2][0] = RD_B(pB, 2, 0); bR[2][1] = RD_B(pB, 2, 1);                          \
    bR[3][0] = RD_B(pB, 3, 0); bR[3][1] = RD_B(pB, 3, 1);                          \
    aR2[0][0] = RD_A(pA, 4, 0); aR2[0][1] = RD_A(pA, 4, 1);                        \
    aR2[1][0] = RD_A(pA, 5, 0); aR2[1][1] = RD_A(pA, 5, 1);                        \
    STG; BAR(); MFMA_Q(aR1, 0, 2) BAR(); }

// P3: rd aR2b; Q3 = aR2 x bR[0,1] (consumes aR2[0,1] from P2 -- landed)
#define PH3(pA, STG)                                                               \
  { aR2[2][0] = RD_A(pA, 6, 0); aR2[2][1] = RD_A(pA, 6, 1);                        \
    aR2[3][0] = RD_A(pA, 7, 0); aR2[3][1] = RD_A(pA, 7, 1);                        \
    STG; BAR(); MFMA_Q(aR2, 4, 0) BAR(); }

// P4: no reads; Q4 = aR2 x bR[2,3]; counted vmcnt before barrier
#define PH4(STG, VMW)                                                              \
  { STG; VMW; BAR(); MFMA_Q(aR2, 4, 2) BAR(); }

#define PH4F()                                                                     \
  { BAR(); MFMA_Q(aR2, 4, 2) }

    // ---- prologue: A(0) full, B(0) full, B(1) full, A(1).Ah0 = 14 loads ----
    STAGE(ldsA0, gA, 0, 0); STAGE(ldsA0, gA, 1, 0);
    STAGE(ldsB0, gB, 0, 0); STAGE(ldsB0, gB, 1, 0);
    STAGE(ldsB1, gB, 0, 1); STAGE(ldsB1, gB, 1, 1);
    STAGE(ldsA1, gA, 0, 1);
    WAIT_VM(6);   // drain A(0)+B(0); leftover 6 = B(1)+A(1).Ah0
    BAR();

    // ---- main loop: 31 iterations (tiles T=2i, T+1), T = 0..60 ----
    for (int i = 0; i < 31; ++i) {
        const int T = 2 * i;
        PH1(ldsA0, ldsB0, STAGE(ldsA1, gA, 1, T + 1));                   // A(T+1).Ah1
        PH2(ldsA0, ldsB0, );                                             // no stage
        PH3(ldsA0,        STAGE(ldsB0, gB, 0, T + 2));                   // B(T+2).Bh0
        PH4(              STAGE(ldsB0, gB, 1, T + 2), WAIT_VM(4));       // B(T+2).Bh1
        PH1(ldsA1, ldsB1, STAGE(ldsA0, gA, 0, T + 2));                   // A(T+2).Ah0
        PH2(ldsA1, ldsB1, STAGE(ldsA0, gA, 1, T + 2));                   // A(T+2).Ah1
        PH3(ldsA1,        STAGE(ldsB1, gB, 0, T + 3));                   // B(T+3).Bh0
        PH4(              { STAGE(ldsB1, gB, 1, T + 3)                   // B(T+3).Bh1
                            STAGE(ldsA1, gA, 0, T + 3) }, WAIT_VM(6));   // A(T+3).Ah0
    }

    // ---- peeled last pair (tiles 62, 63) ----
    PH1(ldsA0, ldsB0, STAGE(ldsA1, gA, 1, 63));                          // A(63).Ah1
    PH2(ldsA0, ldsB0, );
    PH3(ldsA0, );
    PH4(, WAIT_VM(0));                                                   // all landed
    PH1(ldsA1, ldsB1, );
    PH2(ldsA1, ldsB1, );
    PH3(ldsA1, );
    PH4F();

    // ---- epilogue: C/D layout col = lane&15, row = (lane>>4)*4 + reg ----
    float* C = out + (size_t)z * MDIM * NDIM;
#pragma unroll
    for (int mi = 0; mi < 8; ++mi) {
#pragma unroll
        for (int ni = 0; ni < 4; ++ni) {
            const int col  = nBase + wn * 64 + ni * 16 + lr;
            const int row0 = mBase + wr * 128 + mi * 16 + lkq * 4;
            f32x4 v = acc[mi][ni];
#pragma unroll
            for (int j = 0; j < 4; ++j)
                C[(size_t)(row0 + j) * NDIM + col] = v[j];
        }
    }
}

// ---------------- host launch ----------------
extern "C" void kernel_launch(void* const* d_in, const int* in_sizes, int n_in,
                              void* d_out, int out_size, void* d_ws, size_t ws_size,
                              hipStream_t stream) {
    const float* X  = (const float*)d_in[0];
    const float* QW = (const float*)d_in[1];
    const float* QA = (const float*)d_in[2];
    const float* QB = (const float*)d_in[3];
    const float* KW = (const float*)d_in[4];
    const float* KA = (const float*)d_in[5];
    const float* KB = (const float*)d_in[6];
    const float* VW = (const float*)d_in[7];
    const float* VA = (const float*)d_in[8];
    const float* VB = (const float*)d_in[9];
    float* out = (float*)d_out;

    u16* Xb = (u16*)d_ws;                                        // 64 MiB
    u16* Wb = (u16*)((char*)d_ws + (size_t)MDIM * KDIM * 2);     // 3 x 32 MiB

    (void)hipFuncSetAttribute((const void*)gemm8_kernel,
                              hipFuncAttributeMaxDynamicSharedMemorySize, 131072);

    cvt_x_kernel<<<2048, 256, 0, stream>>>(X, Xb, (MDIM * KDIM) / 8);

    dim3 wgrid(4096 / 64, 4096 / 128, 3);
    merge_w3_kernel<<<wgrid, 256, 0, stream>>>(QW, QA, QB, KW, KA, KB, VW, VA, VB, Wb);

    gemm8_kernel<<<dim3(16 * 32 * 3), dim3(512), 131072, stream>>>(Xb, Wb, out);
}

// Round 7
// 772.674 us; speedup vs baseline: 1.4579x; 1.0442x over previous
//
#include <hip/hip_runtime.h>

// FusedLoRAQKV on MI355X (gfx950).
// Y_p = X @ (W_p + 2 * B_p @ A_p)^T  for p in {Q,K,V}
//
// Pipeline:
//   1. cvt_x:    X fp32 -> bf16
//   2. merge_w3: W' = bf16(W + 2*B@A), all three projections, one launch
//   3. gemm8:    256x256 tile, BK=64, 8 waves, mfma_f32_16x16x32_bf16,
//                XOR-swizzled LDS (0 conflicts), SINGLE-BARRIER PHASES:
//                {BAR; reads; stage; MFMA-last}. No barrier between a
//                wave's reads and its MFMA -> fast waves' MFMA overlaps
//                slow waves' ds_reads (LDS pipe || MFMA pipe), which were
//                measured fully serialized under the 2-barrier structure
//                (MFMA 397us + LDS 369us ~= wall 722us). Compiler-counted
//                lgkm per consuming MFMA; vmcnt(4)@P4 / vmcnt(6)@P8.

typedef unsigned short u16;
typedef __attribute__((ext_vector_type(4))) float  f32x4;
typedef __attribute__((ext_vector_type(8))) __bf16 bf16x8;
typedef __attribute__((ext_vector_type(8))) short  s16x8;

#define MDIM 8192
#define NDIM 4096
#define KDIM 4096

__device__ __forceinline__ u16 f2bf(float f) {
    union { float f; unsigned int u; } v;
    v.f = f;
    unsigned int r = v.u + 0x7FFFu + ((v.u >> 16) & 1u);  // RNE
    return (u16)(r >> 16);
}

// ---------------- Kernel 1: X fp32 -> bf16 ----------------
__global__ void __launch_bounds__(256) cvt_x_kernel(const float* __restrict__ X,
                                                    u16* __restrict__ Xb, int nvec8) {
    int stride = gridDim.x * blockDim.x;
    for (int i = blockIdx.x * blockDim.x + threadIdx.x; i < nvec8; i += stride) {
        f32x4 x0 = ((const f32x4*)X)[2 * i];
        f32x4 x1 = ((const f32x4*)X)[2 * i + 1];
        s16x8 o;
        o[0] = (short)f2bf(x0[0]); o[1] = (short)f2bf(x0[1]);
        o[2] = (short)f2bf(x0[2]); o[3] = (short)f2bf(x0[3]);
        o[4] = (short)f2bf(x1[0]); o[5] = (short)f2bf(x1[1]);
        o[6] = (short)f2bf(x1[2]); o[7] = (short)f2bf(x1[3]);
        ((s16x8*)Xb)[i] = o;
    }
}

// ---------------- Kernel 2: W' = bf16(W + 2*B@A), z = projection ----------------
__global__ void __launch_bounds__(256) merge_w3_kernel(const float* __restrict__ QW,
                                                       const float* __restrict__ QA,
                                                       const float* __restrict__ QB,
                                                       const float* __restrict__ KW,
                                                       const float* __restrict__ KA,
                                                       const float* __restrict__ KB,
                                                       const float* __restrict__ VW,
                                                       const float* __restrict__ VA,
                                                       const float* __restrict__ VB,
                                                       u16* __restrict__ WbAll) {
    const int z = blockIdx.z;
    const float* W  = (z == 0) ? QW : (z == 1) ? KW : VW;
    const float* A  = (z == 0) ? QA : (z == 1) ? KA : VA;
    const float* Bm = (z == 0) ? QB : (z == 1) ? KB : VB;
    u16* Wb = WbAll + (size_t)z * NDIM * KDIM;

    __shared__ float As[16][64];
    const int t  = threadIdx.x;
    const int hb = blockIdx.x * 64;
    const int nb = blockIdx.y * 128;

    {   // stage A[16][hb:hb+64]
        int r = t >> 4, c = (t & 15) * 4;
        *(f32x4*)&As[r][c] = *(const f32x4*)&A[r * 4096 + hb + c];
    }
    __syncthreads();

    const int hl = (t & 7) * 8;
    const int n0 = nb + (t >> 3) * 4;

    float bv[4][16];
    float s[4][8];
#pragma unroll
    for (int i = 0; i < 4; i++) {
        const float* br = &Bm[(size_t)(n0 + i) * 16];
#pragma unroll
        for (int r = 0; r < 16; r++) bv[i][r] = 2.0f * br[r];
        f32x4 w0 = *(const f32x4*)&W[(size_t)(n0 + i) * 4096 + hb + hl];
        f32x4 w1 = *(const f32x4*)&W[(size_t)(n0 + i) * 4096 + hb + hl + 4];
        s[i][0] = w0[0]; s[i][1] = w0[1]; s[i][2] = w0[2]; s[i][3] = w0[3];
        s[i][4] = w1[0]; s[i][5] = w1[1]; s[i][6] = w1[2]; s[i][7] = w1[3];
    }
#pragma unroll
    for (int r = 0; r < 16; r++) {
        f32x4 a0 = *(const f32x4*)&As[r][hl];
        f32x4 a1 = *(const f32x4*)&As[r][hl + 4];
#pragma unroll
        for (int i = 0; i < 4; i++) {
            s[i][0] += bv[i][r] * a0[0]; s[i][1] += bv[i][r] * a0[1];
            s[i][2] += bv[i][r] * a0[2]; s[i][3] += bv[i][r] * a0[3];
            s[i][4] += bv[i][r] * a1[0]; s[i][5] += bv[i][r] * a1[1];
            s[i][6] += bv[i][r] * a1[2]; s[i][7] += bv[i][r] * a1[3];
        }
    }
#pragma unroll
    for (int i = 0; i < 4; i++) {
        s16x8 o;
#pragma unroll
        for (int j = 0; j < 8; j++) o[j] = (short)f2bf(s[i][j]);
        *(s16x8*)&Wb[(size_t)(n0 + i) * 4096 + hb + hl] = o;
    }
}

// ---------------- Kernel 3: 256x256 single-barrier-phase GEMM ----------------
// 8 waves (2M x 4N), per-wave 128x64 out, acc[8][4] f32x4 (16x16x32 MFMA).
// LDS 128 KiB: A[2][256][64] + B[2][256][64] bf16, 16B-chunk XOR swizzle
// (chunk ^= row&7), linear-dst global_load_lds + pre-swizzled source.
//
// Phase = { BAR ; ds_reads ; stage ; [vmcnt] ; MFMA }.  ONE barrier/phase.
//   P1: rd 12 (aR1, bR01); STG; Q1 = aR1 x bR01
//   P2: rd 8  (b23, aR2a); STG; Q2 = aR1 x bR23
//   P3: rd 4  (aR2b);      STG; Q3 = aR2 x bR01
//   P4:                    STG; vmcnt; Q4 = aR2 x bR23
//
// WAR audit (single barrier): every ds_read is consumed by an MFMA in the
// same phase or the next one; the consuming MFMA's compiler lgkm-wait forces
// completion before that wave reaches the NEXT barrier. Stage slots target
// buffers whose last read-completion precedes the stage's opening barrier:
//   A-buf: last read P3 (aR2b/aR2a consumed by Q3 in P3 -> complete < BAR(P4));
//          staged P5/P6 (>= 1 barrier later).  OK
//   B-buf: last read P2 (b23 consumed by Q2 in P2 -> complete < BAR(P3));
//          staged P3/P4 (stage issues AFTER BAR(P3) release).  OK
// Stage slots (iter = tiles T,T+1):
//   P1: A(T+1).Ah1 | P3: B(T+2).Bh0 | P4: B(T+2).Bh1 | P5: A(T+2).Ah0
//   P6: A(T+2).Ah1 | P7: B(T+3).Bh0 | P8: B(T+3).Bh1 + A(T+3).Ah0
// vmcnt audit (2 loads/STAGE): carry into P1 = 6 (B(T+1) 4 + A(T+1).Ah0 2).
//   P4 vmcnt: 6 + P1(2)+P3(2)+P4(2) = 12 -> vmcnt(4) drains B(T+1)+A(T+1)
//             (read P5-P7); leaves B(T+2) 4.
//   P8 vmcnt: 4 + P5(2)+P6(2)+P7(2)+P8(4) = 14 -> vmcnt(6) drains
//             B(T+2)+A(T+2) (read next P1-P3); leaves 6 = next carry. OK
// Barriers carry a "memory" clobber so the compiler cannot hoist ds_reads
// across a barrier into a window where the buffer is being re-staged.

#define BM 256
#define BN 256
#define BK 64

#define BAR() asm volatile("s_barrier" ::: "memory")
#define WAIT_VM(n) asm volatile("s_waitcnt vmcnt(" #n ")" ::: "memory")
#define PRIO(p) __builtin_amdgcn_s_setprio(p)

__global__ void __launch_bounds__(512, 2) gemm8_kernel(const u16* __restrict__ Xb,
                                                       const u16* __restrict__ Wb,
                                                       float* __restrict__ out) {
    extern __shared__ char lds[];

    const int t    = threadIdx.x;
    const int lane = t & 63;
    const int w    = t >> 6;      // wave 0..7
    const int wr   = w >> 2;      // M wave 0..1
    const int wn   = w & 3;       // N wave 0..3
    const int lr   = lane & 15;
    const int lkq  = lane >> 4;
    const int lr7  = lr & 7;

    // XCD-bijective remap: 1536 blocks = 8 XCDs x 192
    int wg = blockIdx.x;
    wg = (wg & 7) * 192 + (wg >> 3);
    const int z  = wg >> 9;
    const int r_ = wg & 511;
    const int nT = r_ & 15;
    const int mT = r_ >> 4;
    const int mBase = mT * BM;
    const int nBase = nT * BN;

    const u16* Wp = Wb + (size_t)z * NDIM * KDIM;
    const char* gA = (const char*)Xb + (size_t)mBase * (KDIM * 2);
    const char* gB = (const char*)Wp + (size_t)nBase * (KDIM * 2);

    char* ldsA0 = lds;
    char* ldsA1 = lds + 32768;
    char* ldsB0 = lds + 65536;
    char* ldsB1 = lds + 98304;

    // staging: 2 x global_load_lds(16B)/wave/half-tile, linear LDS dst,
    // pre-swizzled global source column (involution, rule 21)
    const int blkrow = lane >> 3;
    const int colswz = ((lane & 7) ^ blkrow) << 4;
    const size_t stg0 = (size_t)(((w << 1) | 0) * 8 + blkrow) * (KDIM * 2) + colswz;
    const size_t stg1 = (size_t)(((w << 1) | 1) * 8 + blkrow) * (KDIM * 2) + colswz;
    const int ldsStg0 = (((w << 1) | 0) << 10) + lane * 16;
    const int ldsStg1 = (((w << 1) | 1) << 10) + lane * 16;

#define STAGE(ldsTile, gtile, h, kt)                                              \
  { __builtin_amdgcn_global_load_lds(                                             \
        (const __attribute__((address_space(1))) void*)((gtile) + stg0 +          \
            (size_t)(h) * (128 * KDIM * 2) + (size_t)(kt) * 128),                 \
        (__attribute__((address_space(3))) void*)((ldsTile) + (h) * 16384 + ldsStg0), \
        16, 0, 0);                                                                \
    __builtin_amdgcn_global_load_lds(                                             \
        (const __attribute__((address_space(1))) void*)((gtile) + stg1 +          \
            (size_t)(h) * (128 * KDIM * 2) + (size_t)(kt) * 128),                 \
        (__attribute__((address_space(3))) void*)((ldsTile) + (h) * 16384 + ldsStg1), \
        16, 0, 0); }

    // ds_read: row*128 + (((kk<<2)|lkq) ^ (row&7))*16 ; row&7 == lr7
    const int csA = (lkq << 4) ^ (lr7 << 4);
    const int rA0 = (wr * 128 + lr) * 128;
    const int rB0 = (wn * 64 + lr) * 128;
#define RD_A(tile, mi, kk) (*(const bf16x8*)((tile) + rA0 + (mi) * 2048 + (((kk) << 6) ^ csA)))
#define RD_B(tile, ni, kk) (*(const bf16x8*)((tile) + rB0 + (ni) * 2048 + (((kk) << 6) ^ csA)))

    f32x4 acc[8][4] = {};
    bf16x8 aR1[4][2], aR2[4][2], bR[4][2];

#define MFMA_Q(AF, mbase, nbase)                                                   \
    PRIO(1);                                                                       \
    _Pragma("unroll") for (int mi = 0; mi < 4; ++mi)                               \
    _Pragma("unroll") for (int ni = 0; ni < 2; ++ni)                               \
    _Pragma("unroll") for (int kk = 0; kk < 2; ++kk)                               \
      acc[(mbase) + mi][(nbase) + ni] = __builtin_amdgcn_mfma_f32_16x16x32_bf16(   \
          AF[mi][kk], bR[(nbase) + ni][kk], acc[(mbase) + mi][(nbase) + ni], 0, 0, 0); \
    PRIO(0);

// P1: BAR; 12 reads (consumption order); stage; Q1 = aR1 x bR[0,1]
#define PH1(pA, pB, STG)                                                           \
  { BAR();                                                                         \
    aR1[0][0] = RD_A(pA, 0, 0); aR1[0][1] = RD_A(pA, 0, 1);                        \
    bR[0][0]  = RD_B(pB, 0, 0); bR[0][1]  = RD_B(pB, 0, 1);                        \
    aR1[1][0] = RD_A(pA, 1, 0); aR1[1][1] = RD_A(pA, 1, 1);                        \
    bR[1][0]  = RD_B(pB, 1, 0); bR[1][1]  = RD_B(pB, 1, 1);                        \
    aR1[2][0] = RD_A(pA, 2, 0); aR1[2][1] = RD_A(pA, 2, 1);                        \
    aR1[3][0] = RD_A(pA, 3, 0); aR1[3][1] = RD_A(pA, 3, 1);                        \
    STG; MFMA_Q(aR1, 0, 0) }

// P2: BAR; 8 reads (b23 first -- consumed by this phase's Q2); Q2 = aR1 x bR[2,3]
#define PH2(pA, pB, STG)                                                           \
  { BAR();                                                                         \
    bR[2][0] = RD_B(pB, 2, 0); bR[2][1] = RD_B(pB, 2, 1);                          \
    bR[3][0] = RD_B(pB, 3, 0); bR[3][1] = RD_B(pB, 3, 1);                          \
    aR2[0][0] = RD_A(pA, 4, 0); aR2[0][1] = RD_A(pA, 4, 1);                        \
    aR2[1][0] = RD_A(pA, 5, 0); aR2[1][1] = RD_A(pA, 5, 1);                        \
    STG; MFMA_Q(aR1, 0, 2) }

// P3: BAR; 4 reads; Q3 = aR2 x bR[0,1]
#define PH3(pA, STG)                                                               \
  { BAR();                                                                         \
    aR2[2][0] = RD_A(pA, 6, 0); aR2[2][1] = RD_A(pA, 6, 1);                        \
    aR2[3][0] = RD_A(pA, 7, 0); aR2[3][1] = RD_A(pA, 7, 1);                        \
    STG; MFMA_Q(aR2, 4, 0) }

// P4: BAR; stage; counted vmcnt; Q4 = aR2 x bR[2,3]
#define PH4(STG, VMW)                                                              \
  { BAR(); STG; VMW; MFMA_Q(aR2, 4, 2) }

#define PH4F()                                                                     \
  { BAR(); MFMA_Q(aR2, 4, 2) }

    // ---- prologue: A(0) full, B(0) full, B(1) full, A(1).Ah0 = 14 loads ----
    STAGE(ldsA0, gA, 0, 0); STAGE(ldsA0, gA, 1, 0);
    STAGE(ldsB0, gB, 0, 0); STAGE(ldsB0, gB, 1, 0);
    STAGE(ldsB1, gB, 0, 1); STAGE(ldsB1, gB, 1, 1);
    STAGE(ldsA1, gA, 0, 1);
    WAIT_VM(6);   // drain A(0)+B(0); leftover 6 = B(1)+A(1).Ah0 = steady carry
    // (first phase's BAR makes the drain visible to all waves)

    // ---- main loop: 31 iterations (tiles T=2i, T+1), T = 0..60 ----
    for (int i = 0; i < 31; ++i) {
        const int T = 2 * i;
        PH1(ldsA0, ldsB0, STAGE(ldsA1, gA, 1, T + 1));                   // A(T+1).Ah1
        PH2(ldsA0, ldsB0, );                                             // no stage
        PH3(ldsA0,        STAGE(ldsB0, gB, 0, T + 2));                   // B(T+2).Bh0
        PH4(              STAGE(ldsB0, gB, 1, T + 2), WAIT_VM(4));       // B(T+2).Bh1
        PH1(ldsA1, ldsB1, STAGE(ldsA0, gA, 0, T + 2));                   // A(T+2).Ah0
        PH2(ldsA1, ldsB1, STAGE(ldsA0, gA, 1, T + 2));                   // A(T+2).Ah1
        PH3(ldsA1,        STAGE(ldsB1, gB, 0, T + 3));                   // B(T+3).Bh0
        PH4(              { STAGE(ldsB1, gB, 1, T + 3)                   // B(T+3).Bh1
                            STAGE(ldsA1, gA, 0, T + 3) }, WAIT_VM(6));   // A(T+3).Ah0
    }

    // ---- peeled last pair (tiles 62, 63) ----
    PH1(ldsA0, ldsB0, STAGE(ldsA1, gA, 1, 63));                          // A(63).Ah1
    PH2(ldsA0, ldsB0, );
    PH3(ldsA0, );
    PH4(, WAIT_VM(0));                                                   // all landed
    PH1(ldsA1, ldsB1, );
    PH2(ldsA1, ldsB1, );
    PH3(ldsA1, );
    PH4F();

    // ---- epilogue: C/D layout col = lane&15, row = (lane>>4)*4 + reg ----
    float* C = out + (size_t)z * MDIM * NDIM;
#pragma unroll
    for (int mi = 0; mi < 8; ++mi) {
#pragma unroll
        for (int ni = 0; ni < 4; ++ni) {
            const int col  = nBase + wn * 64 + ni * 16 + lr;
            const int row0 = mBase + wr * 128 + mi * 16 + lkq * 4;
            f32x4 v = acc[mi][ni];
#pragma unroll
            for (int j = 0; j < 4; ++j)
                C[(size_t)(row0 + j) * NDIM + col] = v[j];
        }
    }
}

// ---------------- host launch ----------------
extern "C" void kernel_launch(void* const* d_in, const int* in_sizes, int n_in,
                              void* d_out, int out_size, void* d_ws, size_t ws_size,
                              hipStream_t stream) {
    const float* X  = (const float*)d_in[0];
    const float* QW = (const float*)d_in[1];
    const float* QA = (const float*)d_in[2];
    const float* QB = (const float*)d_in[3];
    const float* KW = (const float*)d_in[4];
    const float* KA = (const float*)d_in[5];
    const float* KB = (const float*)d_in[6];
    const float* VW = (const float*)d_in[7];
    const float* VA = (const float*)d_in[8];
    const float* VB = (const float*)d_in[9];
    float* out = (float*)d_out;

    u16* Xb = (u16*)d_ws;                                        // 64 MiB
    u16* Wb = (u16*)((char*)d_ws + (size_t)MDIM * KDIM * 2);     // 3 x 32 MiB

    (void)hipFuncSetAttribute((const void*)gemm8_kernel,
                              hipFuncAttributeMaxDynamicSharedMemorySize, 131072);

    cvt_x_kernel<<<2048, 256, 0, stream>>>(X, Xb, (MDIM * KDIM) / 8);

    dim3 wgrid(4096 / 64, 4096 / 128, 3);
    merge_w3_kernel<<<wgrid, 256, 0, stream>>>(QW, QA, QB, KW, KA, KB, VW, VA, VB, Wb);

    gemm8_kernel<<<dim3(16 * 32 * 3), dim3(512), 131072, stream>>>(Xb, Wb, out);
}